// Round 8
// baseline (483.873 us; speedup 1.0000x reference)
//
#include <hip/hip_runtime.h>
#include <math.h>

// Problem constants
#define S_  1024
#define B_  8
#define D_  512
#define H_  8
#define HD_ 64
#define FF_ 2048
#define M_  8192   // S*B tokens; token r = s*B_ + b
#define DD_ (D_ * D_)

typedef __attribute__((ext_vector_type(8))) short short8;   // 8 x bf16
typedef __attribute__((ext_vector_type(4))) float f32x4;

static __device__ __forceinline__ unsigned short f2bf(float x) {
  union { float f; unsigned int u; } v; v.f = x;
  unsigned int r = v.u + 0x7fff + ((v.u >> 16) & 1);        // RNE
  return (unsigned short)(r >> 16);
}
static __device__ __forceinline__ float bf2f(unsigned short x) {
  union { unsigned int u; float f; } v; v.u = ((unsigned int)x) << 16;
  return v.f;
}
// pack two floats to 2 bf16 in one u32 (round-to-nearest-away; bias-free enough)
static __device__ __forceinline__ unsigned int pack_bf2(float a, float b) {
  union { float f; unsigned int u; } x, y; x.f = a; y.f = b;
  return ((x.u + 0x8000u) >> 16) | ((y.u + 0x8000u) & 0xffff0000u);
}
// async global->LDS, 16B/lane; LDS dest = wave-uniform base + lane*16
static __device__ __forceinline__ void gl_lds16(const unsigned short* g, unsigned short* l) {
  __builtin_amdgcn_global_load_lds((__attribute__((address_space(1))) void*)(g),
                                   (__attribute__((address_space(3))) void*)(l), 16, 0, 0);
}
// T1 bijective chunked XCD swizzle (m192/m204): hardware assigns XCD = phys%8;
// remap so each XCD owns a CONTIGUOUS logical chunk. Requires nwg % 8 == 0.
static __device__ __forceinline__ int xcd_swz(int phys, int nwg) {
  int cpx = nwg >> 3;
  return (phys & 7) * cpx + (phys >> 3);
}

// ---------------------------------------------------------------------------
// batched weight fp32->bf16 (6 jobs of exactly 1,048,576 elems)
// ---------------------------------------------------------------------------
struct CvtJobs { const float* in[6]; unsigned short* out[6]; };
__global__ __launch_bounds__(256) void wcvt_kernel(CvtJobs j) {
  int job = blockIdx.y;
  int i = (blockIdx.x * 256 + threadIdx.x) * 4;
  float4 v = *(const float4*)(j.in[job] + i);
  unsigned short u[4] = {f2bf(v.x), f2bf(v.y), f2bf(v.z), f2bf(v.w)};
  *(uint2*)(j.out[job] + i) = *(const uint2*)u;
}

// activations: job0 src->src16, job1 srcd->srcd16, job2 (src+pos)->qkin16
__global__ __launch_bounds__(256) void acvt_kernel(const float* __restrict__ src,
    const float* __restrict__ srcd, const float* __restrict__ pos,
    unsigned short* __restrict__ src16, unsigned short* __restrict__ srcd16,
    unsigned short* __restrict__ qkin16) {
  int job = blockIdx.y;
  int i = (blockIdx.x * 256 + threadIdx.x) * 4;
  const float* a = (job == 0) ? src : (job == 1) ? srcd : src;
  float4 v = *(const float4*)(a + i);
  if (job == 2) {
    float4 p = *(const float4*)(pos + i);
    v.x += p.x; v.y += p.y; v.z += p.z; v.w += p.w;
  }
  unsigned short* o = (job == 0) ? src16 : (job == 1) ? srcd16 : qkin16;
  unsigned short u[4] = {f2bf(v.x), f2bf(v.y), f2bf(v.z), f2bf(v.w)};
  *(uint2*)(o + i) = *(const uint2*)u;
}

// ---------------------------------------------------------------------------
// bf16 MFMA GEMM body, WIDE-ACC geometry (arithmetic-intensity fix):
//   Y = X @ W^T + bias (+res) (+relu)
// Block tile 128x256, BK=32, 256 thr = 4 waves (2x2), per-wave 64x128 out,
// acc[4][8] (128 VGPR). Per wave per K-tile: 12 ds_read_b128 (12KB) +
// ~6KB stage share = 144 cyc LDS-port vs 32 MFMA = 160 cyc -> MFMA-bound
// (old 64x64/wave geometry was 96 cyc LDS vs 80 cyc MFMA: LDS-port-bound,
// which is why every schedule/occupancy knob was null).
// 2-phase prefetch (round-7 proven), one __syncthreads per K-tile.
// Swizzle (4 slots of 16B per row): LDS slot s of row r holds global chunk
// s ^ ((r>>1)&3); staged via pre-swizzled GLOBAL source (rule #21); reader
// slot g ^ ((ml>>1)&3) -> 2 lanes/bank-quad (optimal).
// LDS: 2 buf x (A 8KB + B 16KB) = 48 KB; ~210 VGPR -> 2 blocks/CU (8 waves).
// ---------------------------------------------------------------------------
static __device__ __forceinline__ void mgemm_body(
    const unsigned short* __restrict__ X, const unsigned short* __restrict__ W,
    const float* __restrict__ bias, const float* __restrict__ resf,
    const unsigned short* __restrict__ resb, unsigned short* __restrict__ Yb,
    float* __restrict__ Yf, int N, int K, int relu, int bx, int by,
    unsigned short* As, unsigned short* Bs)
{
  int tid = threadIdx.x;
  int lane = tid & 63, w = tid >> 6;
  int ml = lane & 15, g = lane >> 4;
  int wm = w >> 1, wn = w & 1;
  int m0 = by * 128, n0 = bx * 256;
  int mxs = (ml >> 1) & 3;               // reader swizzle term

  // staging rows: lrow = tid>>2 (A: lrow, lrow+64; B: lrow, +64, +128, +192).
  // (r+64k)>>1 & 3 == (r>>1)&3 (64/2 % 4 == 0), so one swizzled col serves all.
  int lrow = tid >> 2;
  int sg = (tid & 3) ^ ((lrow >> 1) & 3);
  const unsigned short* gA = X + (size_t)(m0 + lrow) * K + sg * 8;
  const unsigned short* gB = W + (size_t)(n0 + lrow) * K + sg * 8;
  unsigned short* lA = As + w * 512;     // wave w stages rows w*16..+15 of each 64-row group
  unsigned short* lB = Bs + w * 512;

  f32x4 acc[4][8];
  #pragma unroll
  for (int i = 0; i < 4; i++)
    #pragma unroll
    for (int j = 0; j < 8; j++) acc[i][j] = (f32x4){0.f, 0.f, 0.f, 0.f};

  int NT = K >> 5;

  auto STAGE = [&](int buf, int kt) {
    const unsigned short* ga = gA + kt * 32;
    const unsigned short* gb = gB + kt * 32;
    unsigned short* la = lA + buf * 4096;       // A buffers: 128*32 = 4096 u16
    unsigned short* lb = lB + buf * 8192;       // B buffers: 256*32 = 8192 u16
    gl_lds16(ga, la);
    gl_lds16(ga + (size_t)64 * K, la + 2048);
    gl_lds16(gb, lb);
    gl_lds16(gb + (size_t)64 * K, lb + 2048);
    gl_lds16(gb + (size_t)128 * K, lb + 4096);
    gl_lds16(gb + (size_t)192 * K, lb + 6144);
  };

  STAGE(0, 0);
  __syncthreads();                       // tile 0 resident

  for (int kt = 0; kt < NT; kt++) {
    int cur = kt & 1;
    if (kt + 1 < NT) STAGE(cur ^ 1, kt + 1);   // prefetch overlaps ds_read+MFMA

    const unsigned short* lAc = As + cur * 4096;
    const unsigned short* lBc = Bs + cur * 8192;
    short8 af[4], bfr[8];
    #pragma unroll
    for (int i = 0; i < 4; i++) {
      int r = wm * 64 + i * 16 + ml;
      af[i] = *(const short8*)&lAc[r * 32 + ((g ^ mxs) * 8)];
    }
    #pragma unroll
    for (int j = 0; j < 8; j++) {
      int r = wn * 128 + j * 16 + ml;
      bfr[j] = *(const short8*)&lBc[r * 32 + ((g ^ mxs) * 8)];
    }
    #pragma unroll
    for (int i = 0; i < 4; i++)
      #pragma unroll
      for (int j = 0; j < 8; j++)
        acc[i][j] = __builtin_amdgcn_mfma_f32_16x16x32_bf16(af[i], bfr[j], acc[i][j], 0, 0, 0);

    __syncthreads();                     // next tile resident + all reads of cur done
  }

  #pragma unroll
  for (int i = 0; i < 4; i++) {
    int grow = m0 + wm * 64 + i * 16 + g * 4;
    #pragma unroll
    for (int j = 0; j < 8; j++) {
      int gcol = n0 + wn * 128 + j * 16 + ml;
      float bv = bias[gcol];
      #pragma unroll
      for (int r = 0; r < 4; r++) {
        size_t idx = (size_t)(grow + r) * N + gcol;
        float v = acc[i][j][r] + bv;
        if (resf) v += resf[idx];
        if (resb) v += bf2f(resb[idx]);
        if (relu) v = fmaxf(v, 0.0f);
        if (Yb) Yb[idx] = f2bf(v);
        if (Yf) Yf[idx] = v;
      }
    }
  }
}

// QKV mega-launch (256-col tiles): bx<4 img q,k (N=1024) | bx<6 img v (N=512)
// | else dpt qkv (N=1536)
__global__ __launch_bounds__(256, 2) void qkv_kernel(
    const unsigned short* __restrict__ qkin, const unsigned short* __restrict__ src16,
    const unsigned short* __restrict__ srcd16,
    const unsigned short* __restrict__ w_i, const unsigned short* __restrict__ w_d,
    const float* __restrict__ bA_i, const float* __restrict__ bA_d,
    unsigned short* __restrict__ qkimg, unsigned short* __restrict__ vimg,
    unsigned short* __restrict__ dptqkv)
{
  __shared__ unsigned short As[2 * 128 * 32];
  __shared__ unsigned short Bs[2 * 256 * 32];
  // T1: phys -> logical so each XCD owns contiguous by-rows (X-panel L2 reuse)
  int phys = blockIdx.x + 12 * blockIdx.y;
  int L = xcd_swz(phys, 12 * 64);
  int bx = L % 12, by = L / 12;
  if (bx < 4)
    mgemm_body(qkin, w_i, bA_i, nullptr, nullptr, qkimg, nullptr, 1024, 512, 0, bx, by, As, Bs);
  else if (bx < 6)
    mgemm_body(src16, w_i + 2 * DD_, bA_i + 1024, nullptr, nullptr, vimg, nullptr, 512, 512, 0, bx - 4, by, As, Bs);
  else
    mgemm_body(srcd16, w_d, bA_d, nullptr, nullptr, dptqkv, nullptr, 1536, 512, 0, bx - 6, by, As, Bs);
}

// img/dpt pair GEMM: z selects stream (decoded from swizzled logical id)
__global__ __launch_bounds__(256, 2) void pgemm_kernel(
    const unsigned short* __restrict__ X0, const unsigned short* __restrict__ X1,
    const unsigned short* __restrict__ W0, const unsigned short* __restrict__ W1,
    const float* __restrict__ b0, const float* __restrict__ b1,
    const float* __restrict__ rf0, const float* __restrict__ rf1,
    const unsigned short* __restrict__ rb0, const unsigned short* __restrict__ rb1,
    unsigned short* __restrict__ Y0, unsigned short* __restrict__ Y1,
    int N, int K, int relu)
{
  __shared__ unsigned short As[2 * 128 * 32];
  __shared__ unsigned short Bs[2 * 256 * 32];
  int nbx = gridDim.x;
  int nwg = nbx * 64 * 2;
  int phys = blockIdx.x + nbx * (blockIdx.y + 64 * blockIdx.z);
  int L = xcd_swz(phys, nwg);
  int bx = L % nbx; int rem = L / nbx;
  int by = rem % 64; int z = rem / 64;
  mgemm_body(z ? X1 : X0, z ? W1 : W0, z ? b1 : b0, z ? rf1 : rf0,
             z ? rb1 : rb0, z ? Y1 : Y0, nullptr, N, K, relu,
             bx, by, As, Bs);
}

// ---------------------------------------------------------------------------
// V transpose pair: v [M, ld] token-major head slice -> vt [B*H][64][1024]
// ---------------------------------------------------------------------------
__global__ __launch_bounds__(256) void vtrans_kernel(
    const unsigned short* __restrict__ v0, int ld0, unsigned short* __restrict__ vt0,
    const unsigned short* __restrict__ v1, int ld1, unsigned short* __restrict__ vt1)
{
  __shared__ unsigned short tile[64][72];
  const unsigned short* v = blockIdx.z ? v1 : v0;
  unsigned short* vt = blockIdx.z ? vt1 : vt0;
  int ld = blockIdx.z ? ld1 : ld0;
  int bh = blockIdx.y, b = bh >> 3, h = bh & 7;
  int s0 = blockIdx.x * 64;
  int tid = threadIdx.x;
  #pragma unroll
  for (int t = 0; t < 2; t++) {
    int idx = t * 256 + tid;
    int i = idx >> 3, c8 = (idx & 7) * 8;
    *(uint4*)&tile[i][c8] =
        *(const uint4*)(v + ((size_t)(s0 + i) * B_ + b) * ld + h * HD_ + c8);
  }
  __syncthreads();
  int hd = tid >> 2, j0 = (tid & 3) * 16;
  unsigned short tmp[16];
  #pragma unroll
  for (int j = 0; j < 16; j++) tmp[j] = tile[j0 + j][hd];
  unsigned short* dst = vt + ((size_t)bh * HD_ + hd) * S_ + s0 + j0;
  *(uint4*)(dst) = *(const uint4*)&tmp[0];
  *(uint4*)(dst + 8) = *(const uint4*)&tmp[8];
}

// ---------------------------------------------------------------------------
// LayerNorm pair, bf16 in: rows 0..8191 stream0, 8192..16383 stream1
// ---------------------------------------------------------------------------
__global__ __launch_bounds__(256) void ln16_kernel(
    const unsigned short* __restrict__ X0, const unsigned short* __restrict__ X1,
    unsigned short* __restrict__ Yb0, unsigned short* __restrict__ Yb1,
    float* __restrict__ Yf0, float* __restrict__ Yf1,
    const float* __restrict__ gb0, const float* __restrict__ gb1)
{
  int row = blockIdx.x, tid = threadIdx.x;
  int strm = row >> 13, r = row & 8191;
  const unsigned short* X = strm ? X1 : X0;
  unsigned short* Yb = strm ? Yb1 : Yb0;
  float* Yf = strm ? Yf1 : Yf0;
  const float* gb = strm ? gb1 : gb0;       // gamma at [0,512), beta at [512,1024)

  ushort2 xv = *(const ushort2*)(X + (size_t)r * D_ + 2 * tid);
  float v0 = bf2f(xv.x), v1 = bf2f(xv.y);
  float s = v0 + v1, q = v0 * v0 + v1 * v1;
  #pragma unroll
  for (int msk = 1; msk < 64; msk <<= 1) {
    s += __shfl_xor(s, msk);
    q += __shfl_xor(q, msk);
  }
  __shared__ float ss[4], qs[4];
  int wid = tid >> 6;
  if ((tid & 63) == 0) { ss[wid] = s; qs[wid] = q; }
  __syncthreads();
  s = ss[0] + ss[1] + ss[2] + ss[3];
  q = qs[0] + qs[1] + qs[2] + qs[3];
  float mean = s * (1.0f / D_);
  float var  = q * (1.0f / D_) - mean * mean;
  float inv  = rsqrtf(var + 1e-5f);
  float2 gg = *(const float2*)(gb + 2 * tid);
  float2 bb = *(const float2*)(gb + 512 + 2 * tid);
  float o0 = (v0 - mean) * inv * gg.x + bb.x;
  float o1 = (v1 - mean) * inv * gg.y + bb.y;
  if (Yb) {
    unsigned short u[2] = {f2bf(o0), f2bf(o1)};
    *(unsigned int*)(Yb + (size_t)r * D_ + 2 * tid) = *(const unsigned int*)u;
  }
  if (Yf) {
    float2 o; o.x = o0; o.y = o1;
    *(float2*)(Yf + (size_t)r * D_ + 2 * tid) = o;
  }
}

// ---------------------------------------------------------------------------
// MFMA dual-stream cross-blended flash attention v2+T1 (round-4/7 proven form).
// Q-tile 128/block (4 waves x 32 q, 2 msets of 16). K-tiles of 64.
// QK computed TRANSPOSED (A=K,B=Q -> C'[key][q]) so P packs along regs ->
// Pl written as b64; K/V staged via global_load_lds into unpadded [64][64]
// tiles with XOR-chunk swizzle (conflict-free frag reads).
// Pl row stride 72 u16 (144 B = 9 bank-quads): reads 2 lanes/quad, writes
// 2 lanes/pair — both at the floor.
// T1 chunked swizzle: 8 q-blocks of one head colocate on an XCD.
// Plain exp (logits tiny) == exact softmax. 4 accumulators, blend at end.
// ---------------------------------------------------------------------------
__global__ __launch_bounds__(256, 2) void attn_kernel(
    const unsigned short* __restrict__ Qi, const unsigned short* __restrict__ Ki, int ldi,
    const unsigned short* __restrict__ Vti,
    const unsigned short* __restrict__ Qd, const unsigned short* __restrict__ Kd, int ldd,
    const unsigned short* __restrict__ Vtd,
    unsigned short* __restrict__ oi, unsigned short* __restrict__ od)
{
  __shared__ __align__(16) unsigned short Kls[2][64 * 64];   // [stream][key][dim] swizzled
  __shared__ __align__(16) unsigned short Vls[2][64 * 64];   // [stream][dim][key] swizzled
  __shared__ __align__(16) unsigned short Pl[4][2][16 * 72]; // [wave][stream][q][key] pad 72

  int tid = threadIdx.x;
  int phys = blockIdx.x + 8 * blockIdx.y;
  int L = xcd_swz(phys, 8 * 64);
  int bh = L >> 3, b = bh >> 3, h = bh & 7;
  int q0 = (L & 7) * 128;
  int lane = tid & 63, w = tid >> 6;
  int ml = lane & 15, g = lane >> 4;
  int mx = ml & 7;                       // row-swizzle term for frag reads

  // Q fragments: [mset][stream][khalf]; lane holds Q[q=ml of mset][dims g*8(+32)]
  short8 qf[2][2][2];
  #pragma unroll
  for (int t = 0; t < 2; t++) {
    size_t tok = (size_t)(q0 + w * 32 + t * 16 + ml) * B_ + b;
    const unsigned short* qa_i = Qi + tok * ldi + h * HD_ + g * 8;
    const unsigned short* qa_d = Qd + tok * ldd + h * HD_ + g * 8;
    qf[t][0][0] = *(const short8*)(qa_i);  qf[t][0][1] = *(const short8*)(qa_i + 32);
    qf[t][1][0] = *(const short8*)(qa_d);  qf[t][1][1] = *(const short8*)(qa_d + 32);
  }

  // staging role per wave: w0->K img, w1->K dpt, w2->V img, w3->V dpt
  int srow = lane >> 3;                  // 0..7
  int chg = (lane & 7) ^ srow;           // global chunk for this lane's LDS slot
  const unsigned short* gbase; size_t s1, s2; unsigned short* lbase;
  if (w == 0)      { gbase = Ki  + ((size_t)srow * B_ + b) * ldi + h * HD_ + chg * 8; s1 = (size_t)B_ * ldi; s2 = s1; lbase = &Kls[0][0]; }
  else if (w == 1) { gbase = Kd  + ((size_t)srow * B_ + b) * ldd + h * HD_ + chg * 8; s1 = (size_t)B_ * ldd; s2 = s1; lbase = &Kls[1][0]; }
  else if (w == 2) { gbase = Vti + (size_t)bh * HD_ * S_ + (size_t)srow * S_ + chg * 8; s1 = S_; s2 = 1; lbase = &Vls[0][0]; }
  else             { gbase = Vtd + (size_t)bh * HD_ * S_ + (size_t)srow * S_ + chg * 8; s1 = S_; s2 = 1; lbase = &Vls[1][0]; }

  f32x4 acc4[2][4][4];                   // [mset][combo: ii,di,id,dd][hd-tile]
  #pragma unroll
  for (int t = 0; t < 2; t++)
    #pragma unroll
    for (int cb = 0; cb < 4; cb++)
      #pragma unroll
      for (int n = 0; n < 4; n++) acc4[t][cb][n] = (f32x4){0.f, 0.f, 0.f, 0.f};
  float lI[2] = {0.f, 0.f}, lD[2] = {0.f, 0.f};
  const float scale = 0.125f;

  for (int kt = 0; kt < S_ / 64; kt++) {
    int k0 = kt * 64;
    __syncthreads();
    {
      const unsigned short* gp = gbase + (size_t)k0 * s2;
      #pragma unroll
      for (int rr = 0; rr < 8; rr++)
        gl_lds16(gp + (size_t)rr * 8 * s1, lbase + rr * 512);
    }
    __syncthreads();

    #pragma unroll
    for (int t = 0; t < 2; t++) {
      // ---- QK^T transposed: C'[key][q], key tiles n of 16 ----
      #pragma unroll
      for (int st = 0; st < 2; st++) {
        float* ls = st ? &lD[t] : &lI[t];
        const unsigned short* Kt = &Kls[st][0];
        #pragma unroll
        for (int n = 0; n < 4; n++) {
          int rbase = (n * 16 + ml) * 64;
          short8 kf0 = *(const short8*)&Kt[rbase + ((g ^ mx) * 8)];
          short8 kf1 = *(const short8*)&Kt[rbase + (((g + 4) ^ mx) * 8)];
          f32x4 a = (f32x4){0.f, 0.f, 0.f, 0.f};
          a = __builtin_amdgcn_mfma_f32_16x16x32_bf16(kf0, qf[t][st][0], a, 0, 0, 0);
          a = __builtin_amdgcn_mfma_f32_16x16x32_bf16(kf1, qf[t][st][1], a, 0, 0, 0);
          float p0 = __expf(a[0] * scale), p1 = __expf(a[1] * scale);
          float p2 = __expf(a[2] * scale), p3 = __expf(a[3] * scale);
          *ls += (p0 + p1) + (p2 + p3);
          uint2 pk; pk.x = pack_bf2(p0, p1); pk.y = pack_bf2(p2, p3);
          *(uint2*)&Pl[w][st][ml * 72 + n * 16 + g * 4] = pk;   // P[q=ml][key n*16+g*4..+3]
        }
      }
      // ---- PV: 4 combos, key-dim 64 in 2 chunks of 32 ----
      #pragma unroll
      for (int c = 0; c < 2; c++) {
        short8 pI = *(const short8*)&Pl[w][0][ml * 72 + g * 8 + c * 32];
        short8 pD = *(const short8*)&Pl[w][1][ml * 72 + g * 8 + c * 32];
        #pragma unroll
        for (int n = 0; n < 4; n++) {
          int rbase = (n * 16 + ml) * 64;
          int sc = (((g + 4 * c) ^ mx)) * 8;
          short8 vI = *(const short8*)&Vls[0][rbase + sc];
          short8 vD = *(const short8*)&Vls[1][rbase + sc];
          acc4[t][0][n] = __builtin_amdgcn_mfma_f32_16x16x32_bf16(pI, vI, acc4[t][0][n], 0, 0, 0);
          acc4[t][1][n] = __builtin_amdgcn_mfma_f32_16x16x32_bf16(pD, vI, acc4[t][1][n], 0, 0, 0);
          acc4[t][2][n] = __builtin_amdgcn_mfma_f32_16x16x32_bf16(pI, vD, acc4[t][2][n], 0, 0, 0);
          acc4[t][3][n] = __builtin_amdgcn_mfma_f32_16x16x32_bf16(pD, vD, acc4[t][3][n], 0, 0, 0);
        }
      }
    }
  }

  // denominators: lane holds partial (its 16 keys/ktile) for q=ml; reduce over g
  #pragma unroll
  for (int t = 0; t < 2; t++) {
    lI[t] += __shfl_xor(lI[t], 16);  lI[t] += __shfl_xor(lI[t], 32);
    lD[t] += __shfl_xor(lD[t], 16);  lD[t] += __shfl_xor(lD[t], 32);
  }
  #pragma unroll
  for (int t = 0; t < 2; t++) {
    float invI = 1.0f / lI[t], invD = 1.0f / lD[t];
    #pragma unroll
    for (int r = 0; r < 4; r++) {
      float iI = __shfl(invI, g * 4 + r, 16);     // denom lives at lane ml == q row
      float iD = __shfl(invD, g * 4 + r, 16);
      int qrow = q0 + w * 32 + t * 16 + g * 4 + r;
      size_t ob = ((size_t)qrow * B_ + b) * D_ + h * HD_;
      #pragma unroll
      for (int n = 0; n < 4; n++) {
        oi[ob + n * 16 + ml] = f2bf(0.5f * (acc4[t][0][n][r] * iI + acc4[t][1][n][r] * iD));
        od[ob + n * 16 + ml] = f2bf(0.5f * (acc4[t][3][n][r] * iD + acc4[t][2][n][r] * iI));
      }
    }
  }
}

// ---------------------------------------------------------------------------
extern "C" void kernel_launch(void* const* d_in, const int* in_sizes, int n_in,
                              void* d_out, int out_size, void* d_ws, size_t ws_size,
                              hipStream_t stream) {
  const float* src  = (const float*)d_in[0];
  const float* srcd = (const float*)d_in[1];
  const float* pos  = (const float*)d_in[2];
  const float* wA_i = (const float*)d_in[3];
  const float* bA_i = (const float*)d_in[4];
  const float* wA_d = (const float*)d_in[5];
  const float* bA_d = (const float*)d_in[6];
  const float* w1_i = (const float*)d_in[7];
  const float* b1_i = (const float*)d_in[8];
  const float* w2_i = (const float*)d_in[9];
  const float* b2_i = (const float*)d_in[10];
  const float* w1_d = (const float*)d_in[11];
  const float* b1_d = (const float*)d_in[12];
  const float* w2_d = (const float*)d_in[13];
  const float* b2_d = (const float*)d_in[14];
  const float* ln_i = (const float*)d_in[15];
  const float* ln_d = (const float*)d_in[16];

  float* out = (float*)d_out;
  unsigned short* u = (unsigned short*)d_ws;
  const size_t T4 = (size_t)M_ * D_;          // 4,194,304
  const size_t WSZ = (size_t)FF_ * D_;        // 1,048,576 (== 4*DD_)

  // ---- workspace layout (units of T4 ushorts = 8.39 MB; total 113.2 MB) ----
  unsigned short* src16  = u;                 // [0,1) -> vt_i after QKV
  unsigned short* srcd16 = u + T4;            // [1,2) -> vt_d after QKV
  unsigned short* qkimg  = u + 2 * T4;        // [2,4)  [M,1024]
  unsigned short* vimg   = u + 4 * T4;        // [4,5)  [M,512]
  unsigned short* dptqkv = u + 5 * T4;        // [5,8)  [M,1536]
  unsigned short* w_i16  = u + 8 * T4;        // weights: 6 x 1,048,576
  unsigned short* w_d16  = w_i16 + WSZ;
  unsigned short* w1i16  = w_d16 + WSZ;
  unsigned short* w2i16  = w1i16 + WSZ;
  unsigned short* w1d16  = w2i16 + WSZ;
  unsigned short* w2d16  = w1d16 + WSZ;
  unsigned short* t16_i  = w2d16 + WSZ;       // [9.5,10.5) pre-LN bf16
  unsigned short* t16_d  = t16_i + T4;        // [10.5,11.5)
  unsigned short* x16_i  = t16_d + T4;        // [11.5,12.5) post-LN1
  unsigned short* x16_d  = x16_i + T4;        // [12.5,13.5)
  unsigned short* vt_i   = src16;             // reuse after QKV
  unsigned short* vt_d   = srcd16;
  unsigned short* h16_i  = u;                 // [0,4) FFN hidden (post-attn reuse)
  unsigned short* h16_d  = u + 4 * T4;        // [4,8)
  // d_out overlays (consumed before final LN writes)
  unsigned short* qkin16 = (unsigned short*)out;          // bytes [0, 2T4)
  unsigned short* oi16   = (unsigned short*)out;          // bytes [0, 2T4)
  unsigned short* od16   = (unsigned short*)out + T4;     // bytes [2T4, 4T4)

  dim3 blk(256);

  CvtJobs cj;
  cj.in[0] = wA_i; cj.out[0] = w_i16;
  cj.in[1] = wA_d; cj.out[1] = w_d16;
  cj.in[2] = w1_i; cj.out[2] = w1i16;
  cj.in[3] = w2_i; cj.out[3] = w2i16;
  cj.in[4] = w1_d; cj.out[4] = w1d16;
  cj.in[5] = w2_d; cj.out[5] = w2d16;
  wcvt_kernel<<<dim3(1024, 6), blk, 0, stream>>>(cj);
  acvt_kernel<<<dim3(4096, 3), blk, 0, stream>>>(src, srcd, pos, src16, srcd16, qkin16);

  qkv_kernel<<<dim3(12, 64), blk, 0, stream>>>(qkin16, src16, srcd16, w_i16, w_d16,
                                               bA_i, bA_d, qkimg, vimg, dptqkv);
  vtrans_kernel<<<dim3(16, 64, 2), blk, 0, stream>>>(vimg, 512, vt_i, dptqkv + 1024, 1536, vt_d);

  attn_kernel<<<dim3(S_ / 128, B_ * H_), blk, 0, stream>>>(
      qkimg, qkimg + 512, 1024, vt_i, dptqkv, dptqkv + 512, 1536, vt_d, oi16, od16);

  // out-proj + residual(src fp32) -> pre-LN bf16
  pgemm_kernel<<<dim3(2, 64, 2), blk, 0, stream>>>(
      oi16, od16, w_i16 + 3 * DD_, w_d16 + 3 * DD_, bA_i + 1536, bA_d + 1536,
      src, srcd, nullptr, nullptr, t16_i, t16_d, 512, 512, 0);
  ln16_kernel<<<2 * M_, blk, 0, stream>>>(t16_i, t16_d, x16_i, x16_d,
                                          nullptr, nullptr, ln_i, ln_d);
  pgemm_kernel<<<dim3(8, 64, 2), blk, 0, stream>>>(
      x16_i, x16_d, w1i16, w1d16, b1_i, b1_d,
      nullptr, nullptr, nullptr, nullptr, h16_i, h16_d, 2048, 512, 1);
  pgemm_kernel<<<dim3(2, 64, 2), blk, 0, stream>>>(
      h16_i, h16_d, w2i16, w2d16, b2_i, b2_d,
      nullptr, nullptr, x16_i, x16_d, t16_i, t16_d, 512, 2048, 0);
  ln16_kernel<<<2 * M_, blk, 0, stream>>>(t16_i, t16_d, nullptr, nullptr,
                                          out, out + T4, ln_i + 2 * D_, ln_d + 2 * D_);
}

// Round 9
// 440.003 us; speedup vs baseline: 1.0997x; 1.0997x over previous
//
#include <hip/hip_runtime.h>
#include <math.h>

// Problem constants
#define S_  1024
#define B_  8
#define D_  512
#define H_  8
#define HD_ 64
#define FF_ 2048
#define M_  8192   // S*B tokens; token r = s*B_ + b
#define DD_ (D_ * D_)

typedef __attribute__((ext_vector_type(8))) short short8;   // 8 x bf16
typedef __attribute__((ext_vector_type(4))) float f32x4;

static __device__ __forceinline__ unsigned short f2bf(float x) {
  union { float f; unsigned int u; } v; v.f = x;
  unsigned int r = v.u + 0x7fff + ((v.u >> 16) & 1);        // RNE
  return (unsigned short)(r >> 16);
}
static __device__ __forceinline__ float bf2f(unsigned short x) {
  union { unsigned int u; float f; } v; v.u = ((unsigned int)x) << 16;
  return v.f;
}
// pack two floats to 2 bf16 in one u32 (round-to-nearest-away; bias-free enough)
static __device__ __forceinline__ unsigned int pack_bf2(float a, float b) {
  union { float f; unsigned int u; } x, y; x.f = a; y.f = b;
  return ((x.u + 0x8000u) >> 16) | ((y.u + 0x8000u) & 0xffff0000u);
}
// async global->LDS, 16B/lane; LDS dest = wave-uniform base + lane*16
static __device__ __forceinline__ void gl_lds16(const unsigned short* g, unsigned short* l) {
  __builtin_amdgcn_global_load_lds((__attribute__((address_space(1))) void*)(g),
                                   (__attribute__((address_space(3))) void*)(l), 16, 0, 0);
}
// T1 bijective chunked XCD swizzle (m192/m204): hardware assigns XCD = phys%8;
// remap so each XCD owns a CONTIGUOUS logical chunk. Requires nwg % 8 == 0.
static __device__ __forceinline__ int xcd_swz(int phys, int nwg) {
  int cpx = nwg >> 3;
  return (phys & 7) * cpx + (phys >> 3);
}

// ---------------------------------------------------------------------------
// batched weight fp32->bf16 (6 jobs of exactly 1,048,576 elems)
// ---------------------------------------------------------------------------
struct CvtJobs { const float* in[6]; unsigned short* out[6]; };
__global__ __launch_bounds__(256) void wcvt_kernel(CvtJobs j) {
  int job = blockIdx.y;
  int i = (blockIdx.x * 256 + threadIdx.x) * 4;
  float4 v = *(const float4*)(j.in[job] + i);
  unsigned short u[4] = {f2bf(v.x), f2bf(v.y), f2bf(v.z), f2bf(v.w)};
  *(uint2*)(j.out[job] + i) = *(const uint2*)u;
}

// activations: job0 src->src16, job1 srcd->srcd16, job2 (src+pos)->qkin16
__global__ __launch_bounds__(256) void acvt_kernel(const float* __restrict__ src,
    const float* __restrict__ srcd, const float* __restrict__ pos,
    unsigned short* __restrict__ src16, unsigned short* __restrict__ srcd16,
    unsigned short* __restrict__ qkin16) {
  int job = blockIdx.y;
  int i = (blockIdx.x * 256 + threadIdx.x) * 4;
  const float* a = (job == 0) ? src : (job == 1) ? srcd : src;
  float4 v = *(const float4*)(a + i);
  if (job == 2) {
    float4 p = *(const float4*)(pos + i);
    v.x += p.x; v.y += p.y; v.z += p.z; v.w += p.w;
  }
  unsigned short* o = (job == 0) ? src16 : (job == 1) ? srcd16 : qkin16;
  unsigned short u[4] = {f2bf(v.x), f2bf(v.y), f2bf(v.z), f2bf(v.w)};
  *(uint2*)(o + i) = *(const uint2*)u;
}

// ---------------------------------------------------------------------------
// bf16 MFMA GEMM body, 256-row 8-wave geometry (m230-class structure):
//   Y = X @ W^T + bias (+res) (+relu)
// BM=256, BN=NR*64 (256 or 128), BK=64, 512 thr = 8 waves (2M x 4N),
// per-wave output 128 x NR*16, acc[8][NR]. Per wave per K-tile:
// 64(NR=4) MFMA vs 16+2*NR ds_read_b128 -> ~2x the MFMA/LDS intensity of
// the 128^2 4-wave structure (which plateaued at ~330 TF for 5 rounds;
// m230: 2-phase @256^2 = 682 TF refcheck'd).
// Schedule = round-7 proven 2-phase: STAGE(next) first, ds_read+MFMA,
// ONE __syncthreads per K-tile (drains vmcnt+lgkmcnt; WAR/RAW safe).
// Swizzle (rounds-2-6 verified algebra, [r][64] u16 rows = 8 chunks):
// LDS slot s of row r holds global chunk s^(r&7), staged linearly via
// pre-swizzled GLOBAL source (rule #21); reader chunk (ks*4+g)^(r&7)
// -> 2 lanes/bank-quad per 16-lane phase group (optimal).
// LDS: 2buf x (A 32KB + B NR*8KB) = 128/96 KB -> 1 block/CU, 8 waves.
// ---------------------------------------------------------------------------
template <int NR>
static __device__ __forceinline__ void mgemm8_body(
    const unsigned short* __restrict__ X, const unsigned short* __restrict__ W,
    const float* __restrict__ bias, const float* __restrict__ resf,
    const unsigned short* __restrict__ resb, unsigned short* __restrict__ Yb,
    int N, int K, int relu, int bx, int by,
    unsigned short* As, unsigned short* Bs)
{
  int tid = threadIdx.x;
  int lane = tid & 63, w = tid >> 6;       // 8 waves
  int ml = lane & 15, g = lane >> 4;
  int wm = w >> 2, wn = w & 3;             // 2M x 4N
  int m0 = by * 256, n0 = bx * (NR * 64);

  // staging: thread t covers rows lrow+{0,64,128,192}, slot t&7 (16B chunk);
  // global chunk pre-swizzled: (t&7)^(lrow&7) ((r+64q)&7 == r&7).
  int lrow = tid >> 3;                     // 0..63
  int gcolc = ((tid & 7) ^ (lrow & 7)) * 8;
  const unsigned short* gA = X + (size_t)(m0 + lrow) * K + gcolc;
  const unsigned short* gB = W + (size_t)(n0 + lrow) * K + gcolc;
  unsigned short* lA = As + w * 512;       // wave-uniform base + lane*16B
  unsigned short* lB = Bs + w * 512;

  f32x4 acc[8][NR];
  #pragma unroll
  for (int i = 0; i < 8; i++)
    #pragma unroll
    for (int j = 0; j < NR; j++) acc[i][j] = (f32x4){0.f, 0.f, 0.f, 0.f};

  int NT = K >> 6;

  auto STAGE = [&](int buf, int kt) {      // captures pointers only (r5 lesson)
    const unsigned short* ga = gA + kt * 64;
    const unsigned short* gb = gB + kt * 64;
    unsigned short* la = lA + buf * 16384;
    unsigned short* lb = lB + buf * (NR * 4096);
    #pragma unroll
    for (int q = 0; q < 4; q++)
      gl_lds16(ga + (size_t)q * 64 * K, la + q * 4096);
    #pragma unroll
    for (int q = 0; q < NR; q++)
      gl_lds16(gb + (size_t)q * 64 * K, lb + q * 4096);
  };

  STAGE(0, 0);
  __syncthreads();                         // tile 0 resident

  for (int kt = 0; kt < NT; kt++) {
    int cur = kt & 1;
    if (kt + 1 < NT) STAGE(cur ^ 1, kt + 1);   // prefetch flies across compute

    const unsigned short* lAc = As + cur * 16384;
    const unsigned short* lBc = Bs + cur * (NR * 4096);
    #pragma unroll
    for (int ks = 0; ks < 2; ks++) {
      short8 af[8], bfr[NR];
      #pragma unroll
      for (int i = 0; i < 8; i++) {
        int r = wm * 128 + i * 16 + ml;
        af[i] = *(const short8*)&lAc[r * 64 + (((ks * 4 + g) ^ (r & 7)) * 8)];
      }
      #pragma unroll
      for (int j = 0; j < NR; j++) {
        int r = wn * (NR * 16) + j * 16 + ml;
        bfr[j] = *(const short8*)&lBc[r * 64 + (((ks * 4 + g) ^ (r & 7)) * 8)];
      }
      #pragma unroll
      for (int i = 0; i < 8; i++)
        #pragma unroll
        for (int j = 0; j < NR; j++)
          acc[i][j] = __builtin_amdgcn_mfma_f32_16x16x32_bf16(af[i], bfr[j], acc[i][j], 0, 0, 0);
    }
    __syncthreads();                       // next tile resident; cur fully read
  }

  #pragma unroll
  for (int i = 0; i < 8; i++) {
    int grow = m0 + wm * 128 + i * 16 + g * 4;
    #pragma unroll
    for (int j = 0; j < NR; j++) {
      int gcol = n0 + wn * (NR * 16) + j * 16 + ml;
      float bv = bias[gcol];
      #pragma unroll
      for (int r = 0; r < 4; r++) {
        size_t idx = (size_t)(grow + r) * N + gcol;
        float v = acc[i][j][r] + bv;
        if (resf) v += resf[idx];
        if (resb) v += bf2f(resb[idx]);
        if (relu) v = fmaxf(v, 0.0f);
        Yb[idx] = f2bf(v);
      }
    }
  }
}

// QKV mega-launch (BN=256): bx<4 img q,k (N=1024) | bx<6 img v (N=512) |
// else dpt qkv (N=1536). by in 0..31 (256-row tiles).
__global__ __launch_bounds__(512, 2) void qkv_kernel(
    const unsigned short* __restrict__ qkin, const unsigned short* __restrict__ src16,
    const unsigned short* __restrict__ srcd16,
    const unsigned short* __restrict__ w_i, const unsigned short* __restrict__ w_d,
    const float* __restrict__ bA_i, const float* __restrict__ bA_d,
    unsigned short* __restrict__ qkimg, unsigned short* __restrict__ vimg,
    unsigned short* __restrict__ dptqkv)
{
  __shared__ unsigned short As[2 * 256 * 64];
  __shared__ unsigned short Bs[2 * 256 * 64];
  int phys = blockIdx.x + 12 * blockIdx.y;
  int L = xcd_swz(phys, 12 * 32);
  int bx = L % 12, by = L / 12;
  if (bx < 4)
    mgemm8_body<4>(qkin, w_i, bA_i, nullptr, nullptr, qkimg, 1024, 512, 0, bx, by, As, Bs);
  else if (bx < 6)
    mgemm8_body<4>(src16, w_i + 2 * DD_, bA_i + 1024, nullptr, nullptr, vimg, 512, 512, 0, bx - 4, by, As, Bs);
  else
    mgemm8_body<4>(srcd16, w_d, bA_d, nullptr, nullptr, dptqkv, 1536, 512, 0, bx - 6, by, As, Bs);
}

// img/dpt pair GEMM, template BN: NR=4 (FFN1) or NR=2 (proj/FFN2, keeps
// N=512 grids at 256 full-chip blocks). by in 0..31.
template <int NR>
__global__ __launch_bounds__(512, 2) void pgemm_kernel(
    const unsigned short* __restrict__ X0, const unsigned short* __restrict__ X1,
    const unsigned short* __restrict__ W0, const unsigned short* __restrict__ W1,
    const float* __restrict__ b0, const float* __restrict__ b1,
    const float* __restrict__ rf0, const float* __restrict__ rf1,
    const unsigned short* __restrict__ rb0, const unsigned short* __restrict__ rb1,
    unsigned short* __restrict__ Y0, unsigned short* __restrict__ Y1,
    int N, int K, int relu)
{
  __shared__ unsigned short As[2 * 256 * 64];
  __shared__ unsigned short Bs[2 * NR * 64 * 64];
  int nbx = gridDim.x;
  int nwg = nbx * 32 * 2;
  int phys = blockIdx.x + nbx * (blockIdx.y + 32 * blockIdx.z);
  int L = xcd_swz(phys, nwg);
  int bx = L % nbx; int rem = L / nbx;
  int by = rem % 32; int z = rem / 32;
  mgemm8_body<NR>(z ? X1 : X0, z ? W1 : W0, z ? b1 : b0, z ? rf1 : rf0,
                  z ? rb1 : rb0, z ? Y1 : Y0, N, K, relu, bx, by, As, Bs);
}

// ---------------------------------------------------------------------------
// V transpose pair: v [M, ld] token-major head slice -> vt [B*H][64][1024]
// ---------------------------------------------------------------------------
__global__ __launch_bounds__(256) void vtrans_kernel(
    const unsigned short* __restrict__ v0, int ld0, unsigned short* __restrict__ vt0,
    const unsigned short* __restrict__ v1, int ld1, unsigned short* __restrict__ vt1)
{
  __shared__ unsigned short tile[64][72];
  const unsigned short* v = blockIdx.z ? v1 : v0;
  unsigned short* vt = blockIdx.z ? vt1 : vt0;
  int ld = blockIdx.z ? ld1 : ld0;
  int bh = blockIdx.y, b = bh >> 3, h = bh & 7;
  int s0 = blockIdx.x * 64;
  int tid = threadIdx.x;
  #pragma unroll
  for (int t = 0; t < 2; t++) {
    int idx = t * 256 + tid;
    int i = idx >> 3, c8 = (idx & 7) * 8;
    *(uint4*)&tile[i][c8] =
        *(const uint4*)(v + ((size_t)(s0 + i) * B_ + b) * ld + h * HD_ + c8);
  }
  __syncthreads();
  int hd = tid >> 2, j0 = (tid & 3) * 16;
  unsigned short tmp[16];
  #pragma unroll
  for (int j = 0; j < 16; j++) tmp[j] = tile[j0 + j][hd];
  unsigned short* dst = vt + ((size_t)bh * HD_ + hd) * S_ + s0 + j0;
  *(uint4*)(dst) = *(const uint4*)&tmp[0];
  *(uint4*)(dst + 8) = *(const uint4*)&tmp[8];
}

// ---------------------------------------------------------------------------
// LayerNorm pair, bf16 in: rows 0..8191 stream0, 8192..16383 stream1
// ---------------------------------------------------------------------------
__global__ __launch_bounds__(256) void ln16_kernel(
    const unsigned short* __restrict__ X0, const unsigned short* __restrict__ X1,
    unsigned short* __restrict__ Yb0, unsigned short* __restrict__ Yb1,
    float* __restrict__ Yf0, float* __restrict__ Yf1,
    const float* __restrict__ gb0, const float* __restrict__ gb1)
{
  int row = blockIdx.x, tid = threadIdx.x;
  int strm = row >> 13, r = row & 8191;
  const unsigned short* X = strm ? X1 : X0;
  unsigned short* Yb = strm ? Yb1 : Yb0;
  float* Yf = strm ? Yf1 : Yf0;
  const float* gb = strm ? gb1 : gb0;       // gamma at [0,512), beta at [512,1024)

  ushort2 xv = *(const ushort2*)(X + (size_t)r * D_ + 2 * tid);
  float v0 = bf2f(xv.x), v1 = bf2f(xv.y);
  float s = v0 + v1, q = v0 * v0 + v1 * v1;
  #pragma unroll
  for (int msk = 1; msk < 64; msk <<= 1) {
    s += __shfl_xor(s, msk);
    q += __shfl_xor(q, msk);
  }
  __shared__ float ss[4], qs[4];
  int wid = tid >> 6;
  if ((tid & 63) == 0) { ss[wid] = s; qs[wid] = q; }
  __syncthreads();
  s = ss[0] + ss[1] + ss[2] + ss[3];
  q = qs[0] + qs[1] + qs[2] + qs[3];
  float mean = s * (1.0f / D_);
  float var  = q * (1.0f / D_) - mean * mean;
  float inv  = rsqrtf(var + 1e-5f);
  float2 gg = *(const float2*)(gb + 2 * tid);
  float2 bb = *(const float2*)(gb + 512 + 2 * tid);
  float o0 = (v0 - mean) * inv * gg.x + bb.x;
  float o1 = (v1 - mean) * inv * gg.y + bb.y;
  if (Yb) {
    unsigned short u[2] = {f2bf(o0), f2bf(o1)};
    *(unsigned int*)(Yb + (size_t)r * D_ + 2 * tid) = *(const unsigned int*)u;
  }
  if (Yf) {
    float2 o; o.x = o0; o.y = o1;
    *(float2*)(Yf + (size_t)r * D_ + 2 * tid) = o;
  }
}

// ---------------------------------------------------------------------------
// MFMA dual-stream cross-blended flash attention v2+T1 (round-4/7 proven form).
// Q-tile 128/block (4 waves x 32 q, 2 msets of 16). K-tiles of 64.
// QK computed TRANSPOSED (A=K,B=Q -> C'[key][q]) so P packs along regs ->
// Pl written as b64; K/V staged via global_load_lds into unpadded [64][64]
// tiles with XOR-chunk swizzle (conflict-free frag reads).
// Pl row stride 72 u16 (144 B = 9 bank-quads): reads 2 lanes/quad, writes
// 2 lanes/pair — both at the floor.
// T1 chunked swizzle: 8 q-blocks of one head colocate on an XCD.
// Plain exp (logits tiny) == exact softmax. 4 accumulators, blend at end.
// ---------------------------------------------------------------------------
__global__ __launch_bounds__(256, 2) void attn_kernel(
    const unsigned short* __restrict__ Qi, const unsigned short* __restrict__ Ki, int ldi,
    const unsigned short* __restrict__ Vti,
    const unsigned short* __restrict__ Qd, const unsigned short* __restrict__ Kd, int ldd,
    const unsigned short* __restrict__ Vtd,
    unsigned short* __restrict__ oi, unsigned short* __restrict__ od)
{
  __shared__ __align__(16) unsigned short Kls[2][64 * 64];   // [stream][key][dim] swizzled
  __shared__ __align__(16) unsigned short Vls[2][64 * 64];   // [stream][dim][key] swizzled
  __shared__ __align__(16) unsigned short Pl[4][2][16 * 72]; // [wave][stream][q][key] pad 72

  int tid = threadIdx.x;
  int phys = blockIdx.x + 8 * blockIdx.y;
  int L = xcd_swz(phys, 8 * 64);
  int bh = L >> 3, b = bh >> 3, h = bh & 7;
  int q0 = (L & 7) * 128;
  int lane = tid & 63, w = tid >> 6;
  int ml = lane & 15, g = lane >> 4;
  int mx = ml & 7;                       // row-swizzle term for frag reads

  // Q fragments: [mset][stream][khalf]; lane holds Q[q=ml of mset][dims g*8(+32)]
  short8 qf[2][2][2];
  #pragma unroll
  for (int t = 0; t < 2; t++) {
    size_t tok = (size_t)(q0 + w * 32 + t * 16 + ml) * B_ + b;
    const unsigned short* qa_i = Qi + tok * ldi + h * HD_ + g * 8;
    const unsigned short* qa_d = Qd + tok * ldd + h * HD_ + g * 8;
    qf[t][0][0] = *(const short8*)(qa_i);  qf[t][0][1] = *(const short8*)(qa_i + 32);
    qf[t][1][0] = *(const short8*)(qa_d);  qf[t][1][1] = *(const short8*)(qa_d + 32);
  }

  // staging role per wave: w0->K img, w1->K dpt, w2->V img, w3->V dpt
  int srow = lane >> 3;                  // 0..7
  int chg = (lane & 7) ^ srow;           // global chunk for this lane's LDS slot
  const unsigned short* gbase; size_t s1, s2; unsigned short* lbase;
  if (w == 0)      { gbase = Ki  + ((size_t)srow * B_ + b) * ldi + h * HD_ + chg * 8; s1 = (size_t)B_ * ldi; s2 = s1; lbase = &Kls[0][0]; }
  else if (w == 1) { gbase = Kd  + ((size_t)srow * B_ + b) * ldd + h * HD_ + chg * 8; s1 = (size_t)B_ * ldd; s2 = s1; lbase = &Kls[1][0]; }
  else if (w == 2) { gbase = Vti + (size_t)bh * HD_ * S_ + (size_t)srow * S_ + chg * 8; s1 = S_; s2 = 1; lbase = &Vls[0][0]; }
  else             { gbase = Vtd + (size_t)bh * HD_ * S_ + (size_t)srow * S_ + chg * 8; s1 = S_; s2 = 1; lbase = &Vls[1][0]; }

  f32x4 acc4[2][4][4];                   // [mset][combo: ii,di,id,dd][hd-tile]
  #pragma unroll
  for (int t = 0; t < 2; t++)
    #pragma unroll
    for (int cb = 0; cb < 4; cb++)
      #pragma unroll
      for (int n = 0; n < 4; n++) acc4[t][cb][n] = (f32x4){0.f, 0.f, 0.f, 0.f};
  float lI[2] = {0.f, 0.f}, lD[2] = {0.f, 0.f};
  const float scale = 0.125f;

  for (int kt = 0; kt < S_ / 64; kt++) {
    int k0 = kt * 64;
    __syncthreads();
    {
      const unsigned short* gp = gbase + (size_t)k0 * s2;
      #pragma unroll
      for (int rr = 0; rr < 8; rr++)
        gl_lds16(gp + (size_t)rr * 8 * s1, lbase + rr * 512);
    }
    __syncthreads();

    #pragma unroll
    for (int t = 0; t < 2; t++) {
      // ---- QK^T transposed: C'[key][q], key tiles n of 16 ----
      #pragma unroll
      for (int st = 0; st < 2; st++) {
        float* ls = st ? &lD[t] : &lI[t];
        const unsigned short* Kt = &Kls[st][0];
        #pragma unroll
        for (int n = 0; n < 4; n++) {
          int rbase = (n * 16 + ml) * 64;
          short8 kf0 = *(const short8*)&Kt[rbase + ((g ^ mx) * 8)];
          short8 kf1 = *(const short8*)&Kt[rbase + (((g + 4) ^ mx) * 8)];
          f32x4 a = (f32x4){0.f, 0.f, 0.f, 0.f};
          a = __builtin_amdgcn_mfma_f32_16x16x32_bf16(kf0, qf[t][st][0], a, 0, 0, 0);
          a = __builtin_amdgcn_mfma_f32_16x16x32_bf16(kf1, qf[t][st][1], a, 0, 0, 0);
          float p0 = __expf(a[0] * scale), p1 = __expf(a[1] * scale);
          float p2 = __expf(a[2] * scale), p3 = __expf(a[3] * scale);
          *ls += (p0 + p1) + (p2 + p3);
          uint2 pk; pk.x = pack_bf2(p0, p1); pk.y = pack_bf2(p2, p3);
          *(uint2*)&Pl[w][st][ml * 72 + n * 16 + g * 4] = pk;   // P[q=ml][key n*16+g*4..+3]
        }
      }
      // ---- PV: 4 combos, key-dim 64 in 2 chunks of 32 ----
      #pragma unroll
      for (int c = 0; c < 2; c++) {
        short8 pI = *(const short8*)&Pl[w][0][ml * 72 + g * 8 + c * 32];
        short8 pD = *(const short8*)&Pl[w][1][ml * 72 + g * 8 + c * 32];
        #pragma unroll
        for (int n = 0; n < 4; n++) {
          int rbase = (n * 16 + ml) * 64;
          int sc = (((g + 4 * c) ^ mx)) * 8;
          short8 vI = *(const short8*)&Vls[0][rbase + sc];
          short8 vD = *(const short8*)&Vls[1][rbase + sc];
          acc4[t][0][n] = __builtin_amdgcn_mfma_f32_16x16x32_bf16(pI, vI, acc4[t][0][n], 0, 0, 0);
          acc4[t][1][n] = __builtin_amdgcn_mfma_f32_16x16x32_bf16(pD, vI, acc4[t][1][n], 0, 0, 0);
          acc4[t][2][n] = __builtin_amdgcn_mfma_f32_16x16x32_bf16(pI, vD, acc4[t][2][n], 0, 0, 0);
          acc4[t][3][n] = __builtin_amdgcn_mfma_f32_16x16x32_bf16(pD, vD, acc4[t][3][n], 0, 0, 0);
        }
      }
    }
  }

  // denominators: lane holds partial (its 16 keys/ktile) for q=ml; reduce over g
  #pragma unroll
  for (int t = 0; t < 2; t++) {
    lI[t] += __shfl_xor(lI[t], 16);  lI[t] += __shfl_xor(lI[t], 32);
    lD[t] += __shfl_xor(lD[t], 16);  lD[t] += __shfl_xor(lD[t], 32);
  }
  #pragma unroll
  for (int t = 0; t < 2; t++) {
    float invI = 1.0f / lI[t], invD = 1.0f / lD[t];
    #pragma unroll
    for (int r = 0; r < 4; r++) {
      float iI = __shfl(invI, g * 4 + r, 16);     // denom lives at lane ml == q row
      float iD = __shfl(invD, g * 4 + r, 16);
      int qrow = q0 + w * 32 + t * 16 + g * 4 + r;
      size_t ob = ((size_t)qrow * B_ + b) * D_ + h * HD_;
      #pragma unroll
      for (int n = 0; n < 4; n++) {
        oi[ob + n * 16 + ml] = f2bf(0.5f * (acc4[t][0][n][r] * iI + acc4[t][1][n][r] * iD));
        od[ob + n * 16 + ml] = f2bf(0.5f * (acc4[t][3][n][r] * iD + acc4[t][2][n][r] * iI));
      }
    }
  }
}

// ---------------------------------------------------------------------------
extern "C" void kernel_launch(void* const* d_in, const int* in_sizes, int n_in,
                              void* d_out, int out_size, void* d_ws, size_t ws_size,
                              hipStream_t stream) {
  const float* src  = (const float*)d_in[0];
  const float* srcd = (const float*)d_in[1];
  const float* pos  = (const float*)d_in[2];
  const float* wA_i = (const float*)d_in[3];
  const float* bA_i = (const float*)d_in[4];
  const float* wA_d = (const float*)d_in[5];
  const float* bA_d = (const float*)d_in[6];
  const float* w1_i = (const float*)d_in[7];
  const float* b1_i = (const float*)d_in[8];
  const float* w2_i = (const float*)d_in[9];
  const float* b2_i = (const float*)d_in[10];
  const float* w1_d = (const float*)d_in[11];
  const float* b1_d = (const float*)d_in[12];
  const float* w2_d = (const float*)d_in[13];
  const float* b2_d = (const float*)d_in[14];
  const float* ln_i = (const float*)d_in[15];
  const float* ln_d = (const float*)d_in[16];

  float* out = (float*)d_out;
  unsigned short* u = (unsigned short*)d_ws;
  const size_t T4 = (size_t)M_ * D_;          // 4,194,304
  const size_t WSZ = (size_t)FF_ * D_;        // 1,048,576 (== 4*DD_)

  // ---- workspace layout (units of T4 ushorts = 8.39 MB; total 113.2 MB) ----
  unsigned short* src16  = u;                 // [0,1) -> vt_i after QKV
  unsigned short* srcd16 = u + T4;            // [1,2) -> vt_d after QKV
  unsigned short* qkimg  = u + 2 * T4;        // [2,4)  [M,1024]
  unsigned short* vimg   = u + 4 * T4;        // [4,5)  [M,512]
  unsigned short* dptqkv = u + 5 * T4;        // [5,8)  [M,1536]
  unsigned short* w_i16  = u + 8 * T4;        // weights: 6 x 1,048,576
  unsigned short* w_d16  = w_i16 + WSZ;
  unsigned short* w1i16  = w_d16 + WSZ;
  unsigned short* w2i16  = w1i16 + WSZ;
  unsigned short* w1d16  = w2i16 + WSZ;
  unsigned short* w2d16  = w1d16 + WSZ;
  unsigned short* t16_i  = w2d16 + WSZ;       // [9.5,10.5) pre-LN bf16
  unsigned short* t16_d  = t16_i + T4;        // [10.5,11.5)
  unsigned short* x16_i  = t16_d + T4;        // [11.5,12.5) post-LN1
  unsigned short* x16_d  = x16_i + T4;        // [12.5,13.5)
  unsigned short* vt_i   = src16;             // reuse after QKV
  unsigned short* vt_d   = srcd16;
  unsigned short* h16_i  = u;                 // [0,4) FFN hidden (post-attn reuse)
  unsigned short* h16_d  = u + 4 * T4;        // [4,8)
  // d_out overlays (consumed before final LN writes)
  unsigned short* qkin16 = (unsigned short*)out;          // bytes [0, 2T4)
  unsigned short* oi16   = (unsigned short*)out;          // bytes [0, 2T4)
  unsigned short* od16   = (unsigned short*)out + T4;     // bytes [2T4, 4T4)

  dim3 blk(256);
  dim3 blk512(512);

  CvtJobs cj;
  cj.in[0] = wA_i; cj.out[0] = w_i16;
  cj.in[1] = wA_d; cj.out[1] = w_d16;
  cj.in[2] = w1_i; cj.out[2] = w1i16;
  cj.in[3] = w2_i; cj.out[3] = w2i16;
  cj.in[4] = w1_d; cj.out[4] = w1d16;
  cj.in[5] = w2_d; cj.out[5] = w2d16;
  wcvt_kernel<<<dim3(1024, 6), blk, 0, stream>>>(cj);
  acvt_kernel<<<dim3(4096, 3), blk, 0, stream>>>(src, srcd, pos, src16, srcd16, qkin16);

  qkv_kernel<<<dim3(12, 32), blk512, 0, stream>>>(qkin16, src16, srcd16, w_i16, w_d16,
                                                  bA_i, bA_d, qkimg, vimg, dptqkv);
  vtrans_kernel<<<dim3(16, 64, 2), blk, 0, stream>>>(vimg, 512, vt_i, dptqkv + 1024, 1536, vt_d);

  attn_kernel<<<dim3(S_ / 128, B_ * H_), blk, 0, stream>>>(
      qkimg, qkimg + 512, 1024, vt_i, dptqkv, dptqkv + 512, 1536, vt_d, oi16, od16);

  // out-proj + residual(src fp32) -> pre-LN bf16
  pgemm_kernel<2><<<dim3(4, 32, 2), blk512, 0, stream>>>(
      oi16, od16, w_i16 + 3 * DD_, w_d16 + 3 * DD_, bA_i + 1536, bA_d + 1536,
      src, srcd, nullptr, nullptr, t16_i, t16_d, 512, 512, 0);
  ln16_kernel<<<2 * M_, blk, 0, stream>>>(t16_i, t16_d, x16_i, x16_d,
                                          nullptr, nullptr, ln_i, ln_d);
  pgemm_kernel<4><<<dim3(8, 32, 2), blk512, 0, stream>>>(
      x16_i, x16_d, w1i16, w1d16, b1_i, b1_d,
      nullptr, nullptr, nullptr, nullptr, h16_i, h16_d, 2048, 512, 1);
  pgemm_kernel<2><<<dim3(4, 32, 2), blk512, 0, stream>>>(
      h16_i, h16_d, w2i16, w2d16, b2_i, b2_d,
      nullptr, nullptr, x16_i, x16_d, t16_i, t16_d, 512, 2048, 0);
  ln16_kernel<<<2 * M_, blk, 0, stream>>>(t16_i, t16_d, nullptr, nullptr,
                                          out, out + T4, ln_i + 2 * D_, ln_d + 2 * D_);
}

// Round 11
// 413.901 us; speedup vs baseline: 1.1691x; 1.0631x over previous
//
#include <hip/hip_runtime.h>
#include <math.h>

// Problem constants
#define S_  1024
#define B_  8
#define D_  512
#define H_  8
#define HD_ 64
#define FF_ 2048
#define M_  8192   // S*B tokens; token r = s*B_ + b
#define DD_ (D_ * D_)

typedef __attribute__((ext_vector_type(8))) short short8;   // 8 x bf16
typedef __attribute__((ext_vector_type(4))) float f32x4;

static __device__ __forceinline__ unsigned short f2bf(float x) {
  union { float f; unsigned int u; } v; v.f = x;
  unsigned int r = v.u + 0x7fff + ((v.u >> 16) & 1);        // RNE
  return (unsigned short)(r >> 16);
}
static __device__ __forceinline__ float bf2f(unsigned short x) {
  union { unsigned int u; float f; } v; v.u = ((unsigned int)x) << 16;
  return v.f;
}
// pack two floats to 2 bf16 in one u32 (round-to-nearest-away; bias-free enough)
static __device__ __forceinline__ unsigned int pack_bf2(float a, float b) {
  union { float f; unsigned int u; } x, y; x.f = a; y.f = b;
  return ((x.u + 0x8000u) >> 16) | ((y.u + 0x8000u) & 0xffff0000u);
}
// async global->LDS, 16B/lane; LDS dest = wave-uniform base + lane*16
static __device__ __forceinline__ void gl_lds16(const unsigned short* g, unsigned short* l) {
  __builtin_amdgcn_global_load_lds((__attribute__((address_space(1))) void*)(g),
                                   (__attribute__((address_space(3))) void*)(l), 16, 0, 0);
}
// T1 bijective chunked XCD swizzle (m192/m204): hardware assigns XCD = phys%8;
// remap so each XCD owns a CONTIGUOUS logical chunk. Requires nwg % 8 == 0.
static __device__ __forceinline__ int xcd_swz(int phys, int nwg) {
  int cpx = nwg >> 3;
  return (phys & 7) * cpx + (phys >> 3);
}

// ---------------------------------------------------------------------------
// merged conversion kernel, 1-D grid (no idle blocks):
//   bid < 12288 : acvt job bid/4096 (0: src->src16, 1: srcd->srcd16,
//                 2: src+pos->qkin16), bx = bid%4096
//   else        : wcvt job (bid-12288)/1024, bx = (bid-12288)%1024
// ---------------------------------------------------------------------------
struct CvtArgs {
  const float* win[6]; unsigned short* wout[6];
  const float* src; const float* srcd; const float* pos;
  unsigned short* src16; unsigned short* srcd16; unsigned short* qkin16;
};
__global__ __launch_bounds__(256) void cvt_kernel(CvtArgs a) {
  int bid = blockIdx.x;
  if (bid < 12288) {
    int job = bid >> 12, bx = bid & 4095;
    int i = (bx * 256 + threadIdx.x) * 4;
    const float* in = (job == 0) ? a.src : (job == 1) ? a.srcd : a.src;
    float4 v = *(const float4*)(in + i);
    if (job == 2) {
      float4 p = *(const float4*)(a.pos + i);
      v.x += p.x; v.y += p.y; v.z += p.z; v.w += p.w;
    }
    unsigned short* o = (job == 0) ? a.src16 : (job == 1) ? a.srcd16 : a.qkin16;
    unsigned short u[4] = {f2bf(v.x), f2bf(v.y), f2bf(v.z), f2bf(v.w)};
    *(uint2*)(o + i) = *(const uint2*)u;
  } else {
    int wjob = (bid - 12288) >> 10, bx = (bid - 12288) & 1023;
    int i = (bx * 256 + threadIdx.x) * 4;
    float4 v = *(const float4*)(a.win[wjob] + i);
    unsigned short u[4] = {f2bf(v.x), f2bf(v.y), f2bf(v.z), f2bf(v.w)};
    *(uint2*)(a.wout[wjob] + i) = *(const uint2*)u;
  }
}

// ---------------------------------------------------------------------------
// bf16 MFMA GEMM body, 2-phase double-buffered at 4 blocks/CU (round-7 best):
//   Y = X @ W^T + bias (+res) (+relu)
// 128x128 tile, BK=32, 256 thr = 4 waves (2x2 of 64x64), 16x16x32 MFMA.
// LDS: 2 buf x (A 8KB + B 8KB) = 32 KB; __launch_bounds__(256,4) -> 4 blk/CU.
// Swizzle: LDS slot s of row r holds global chunk s^((r>>1)&3); staged via
// pre-swizzled GLOBAL source (rule #21); reader slot g^((ml>>1)&3) ->
// 2 lanes/bank-quad (optimal).
// ---------------------------------------------------------------------------
static __device__ __forceinline__ void mgemm_body(
    const unsigned short* __restrict__ X, const unsigned short* __restrict__ W,
    const float* __restrict__ bias, const float* __restrict__ resf,
    const unsigned short* __restrict__ resb, unsigned short* __restrict__ Yb,
    float* __restrict__ Yf, int N, int K, int relu, int bx, int by,
    unsigned short* As, unsigned short* Bs)
{
  int tid = threadIdx.x;
  int lane = tid & 63, w = tid >> 6;
  int ml = lane & 15, g = lane >> 4;
  int wm = w >> 1, wn = w & 1;
  int m0 = by * 128, n0 = bx * 128;
  int mxs = (ml >> 1) & 3;               // reader swizzle term

  int lrow = tid >> 2;
  int sg = (tid & 3) ^ ((lrow >> 1) & 3);
  const unsigned short* gA = X + (size_t)(m0 + lrow) * K + sg * 8;
  const unsigned short* gB = W + (size_t)(n0 + lrow) * K + sg * 8;
  unsigned short* lA = As + w * 512;     // wave-uniform base (u16)
  unsigned short* lB = Bs + w * 512;

  f32x4 acc[4][4];
  #pragma unroll
  for (int i = 0; i < 4; i++)
    #pragma unroll
    for (int j = 0; j < 4; j++) acc[i][j] = (f32x4){0.f, 0.f, 0.f, 0.f};

  int NT = K >> 5;

  auto STAGE = [&](int buf, int kt) {
    const unsigned short* ga = gA + kt * 32;
    const unsigned short* gb = gB + kt * 32;
    unsigned short* la = lA + buf * 4096;
    unsigned short* lb = lB + buf * 4096;
    gl_lds16(ga, la);
    gl_lds16(ga + (size_t)64 * K, la + 2048);
    gl_lds16(gb, lb);
    gl_lds16(gb + (size_t)64 * K, lb + 2048);
  };

  STAGE(0, 0);
  __syncthreads();                       // tile 0 resident

  for (int kt = 0; kt < NT; kt++) {
    int cur = kt & 1;
    if (kt + 1 < NT) STAGE(cur ^ 1, kt + 1);   // prefetch overlaps ds_read+MFMA

    const unsigned short* lAc = As + cur * 4096;
    const unsigned short* lBc = Bs + cur * 4096;
    short8 af[4], bfr[4];
    #pragma unroll
    for (int i = 0; i < 4; i++) {
      int r = wm * 64 + i * 16 + ml;
      af[i] = *(const short8*)&lAc[r * 32 + ((g ^ mxs) * 8)];
    }
    #pragma unroll
    for (int j = 0; j < 4; j++) {
      int r = wn * 64 + j * 16 + ml;
      bfr[j] = *(const short8*)&lBc[r * 32 + ((g ^ mxs) * 8)];
    }
    #pragma unroll
    for (int i = 0; i < 4; i++)
      #pragma unroll
      for (int j = 0; j < 4; j++)
        acc[i][j] = __builtin_amdgcn_mfma_f32_16x16x32_bf16(af[i], bfr[j], acc[i][j], 0, 0, 0);

    __syncthreads();                     // next tile resident + all reads of cur done
  }

  #pragma unroll
  for (int i = 0; i < 4; i++) {
    int grow = m0 + wm * 64 + i * 16 + g * 4;
    #pragma unroll
    for (int j = 0; j < 4; j++) {
      int gcol = n0 + wn * 64 + j * 16 + ml;
      float bv = bias[gcol];
      #pragma unroll
      for (int r = 0; r < 4; r++) {
        size_t idx = (size_t)(grow + r) * N + gcol;
        float v = acc[i][j][r] + bv;
        if (resf) v += resf[idx];
        if (resb) v += bf2f(resb[idx]);
        if (relu) v = fmaxf(v, 0.0f);
        if (Yb) Yb[idx] = f2bf(v);
        if (Yf) Yf[idx] = v;
      }
    }
  }
}

// QKV mega-launch: bx<8 img q,k (N=1024) | bx<12 img v (N=512) | else dpt qkv (N=1536)
__global__ __launch_bounds__(256, 4) void qkv_kernel(
    const unsigned short* __restrict__ qkin, const unsigned short* __restrict__ src16,
    const unsigned short* __restrict__ srcd16,
    const unsigned short* __restrict__ w_i, const unsigned short* __restrict__ w_d,
    const float* __restrict__ bA_i, const float* __restrict__ bA_d,
    unsigned short* __restrict__ qkimg, unsigned short* __restrict__ vimg,
    unsigned short* __restrict__ dptqkv)
{
  __shared__ unsigned short As[2 * 128 * 32];
  __shared__ unsigned short Bs[2 * 128 * 32];
  // T1: phys -> logical so each XCD owns contiguous by-rows (X-panel L2 reuse)
  int phys = blockIdx.x + 24 * blockIdx.y;
  int L = xcd_swz(phys, 24 * 64);
  int bx = L % 24, by = L / 24;
  if (bx < 8)
    mgemm_body(qkin, w_i, bA_i, nullptr, nullptr, qkimg, nullptr, 1024, 512, 0, bx, by, As, Bs);
  else if (bx < 12)
    mgemm_body(src16, w_i + 2 * DD_, bA_i + 1024, nullptr, nullptr, vimg, nullptr, 512, 512, 0, bx - 8, by, As, Bs);
  else
    mgemm_body(srcd16, w_d, bA_d, nullptr, nullptr, dptqkv, nullptr, 1536, 512, 0, bx - 12, by, As, Bs);
}

// img/dpt pair GEMM: z selects stream (decoded from swizzled logical id)
__global__ __launch_bounds__(256, 4) void pgemm_kernel(
    const unsigned short* __restrict__ X0, const unsigned short* __restrict__ X1,
    const unsigned short* __restrict__ W0, const unsigned short* __restrict__ W1,
    const float* __restrict__ b0, const float* __restrict__ b1,
    const float* __restrict__ rf0, const float* __restrict__ rf1,
    const unsigned short* __restrict__ rb0, const unsigned short* __restrict__ rb1,
    unsigned short* __restrict__ Y0, unsigned short* __restrict__ Y1,
    int N, int K, int relu)
{
  __shared__ unsigned short As[2 * 128 * 32];
  __shared__ unsigned short Bs[2 * 128 * 32];
  int nbx = gridDim.x;
  int nwg = nbx * 64 * 2;
  int phys = blockIdx.x + nbx * (blockIdx.y + 64 * blockIdx.z);
  int L = xcd_swz(phys, nwg);
  int bx = L % nbx; int rem = L / nbx;
  int by = rem % 64; int z = rem / 64;
  mgemm_body(z ? X1 : X0, z ? W1 : W0, z ? b1 : b0, z ? rf1 : rf0,
             z ? rb1 : rb0, z ? Y1 : Y0, nullptr, N, K, relu,
             bx, by, As, Bs);
}

// ---------------------------------------------------------------------------
// V transpose pair: v [M, ld] token-major head slice -> vt [B*H][64][1024]
// ---------------------------------------------------------------------------
__global__ __launch_bounds__(256) void vtrans_kernel(
    const unsigned short* __restrict__ v0, int ld0, unsigned short* __restrict__ vt0,
    const unsigned short* __restrict__ v1, int ld1, unsigned short* __restrict__ vt1)
{
  __shared__ unsigned short tile[64][72];
  const unsigned short* v = blockIdx.z ? v1 : v0;
  unsigned short* vt = blockIdx.z ? vt1 : vt0;
  int ld = blockIdx.z ? ld1 : ld0;
  int bh = blockIdx.y, b = bh >> 3, h = bh & 7;
  int s0 = blockIdx.x * 64;
  int tid = threadIdx.x;
  #pragma unroll
  for (int t = 0; t < 2; t++) {
    int idx = t * 256 + tid;
    int i = idx >> 3, c8 = (idx & 7) * 8;
    *(uint4*)&tile[i][c8] =
        *(const uint4*)(v + ((size_t)(s0 + i) * B_ + b) * ld + h * HD_ + c8);
  }
  __syncthreads();
  int hd = tid >> 2, j0 = (tid & 3) * 16;
  unsigned short tmp[16];
  #pragma unroll
  for (int j = 0; j < 16; j++) tmp[j] = tile[j0 + j][hd];
  unsigned short* dst = vt + ((size_t)bh * HD_ + hd) * S_ + s0 + j0;
  *(uint4*)(dst) = *(const uint4*)&tmp[0];
  *(uint4*)(dst + 8) = *(const uint4*)&tmp[8];
}

// ---------------------------------------------------------------------------
// LayerNorm pair, wave-per-row (no LDS, no __syncthreads):
// 4 rows/block (one wave each); lane holds 8 elems (short8); 6-level
// __shfl_xor reduce within the wave. Rows 0..8191 stream0, 8192.. stream1.
// ---------------------------------------------------------------------------
__global__ __launch_bounds__(256) void ln16_kernel(
    const unsigned short* __restrict__ X0, const unsigned short* __restrict__ X1,
    unsigned short* __restrict__ Yb0, unsigned short* __restrict__ Yb1,
    float* __restrict__ Yf0, float* __restrict__ Yf1,
    const float* __restrict__ gb0, const float* __restrict__ gb1)
{
  int tid = threadIdx.x;
  int w = tid >> 6, lane = tid & 63;
  int R = blockIdx.x * 4 + w;
  int strm = R >> 13, r = R & 8191;
  const unsigned short* X = strm ? X1 : X0;
  unsigned short* Yb = strm ? Yb1 : Yb0;
  float* Yf = strm ? Yf1 : Yf0;
  const float* gb = strm ? gb1 : gb0;       // gamma at [0,512), beta at [512,1024)

  short8 xv = *(const short8*)(X + (size_t)r * D_ + lane * 8);
  float v[8];
  #pragma unroll
  for (int j = 0; j < 8; j++) v[j] = bf2f((unsigned short)xv[j]);
  float s = 0.f, q = 0.f;
  #pragma unroll
  for (int j = 0; j < 8; j++) { s += v[j]; q += v[j] * v[j]; }
  #pragma unroll
  for (int msk = 1; msk < 64; msk <<= 1) {
    s += __shfl_xor(s, msk);
    q += __shfl_xor(q, msk);
  }
  float mean = s * (1.0f / D_);
  float var  = q * (1.0f / D_) - mean * mean;
  float inv  = rsqrtf(var + 1e-5f);
  float4 g0 = *(const float4*)(gb + lane * 8);
  float4 g1 = *(const float4*)(gb + lane * 8 + 4);
  float4 b0 = *(const float4*)(gb + 512 + lane * 8);
  float4 b1 = *(const float4*)(gb + 512 + lane * 8 + 4);
  float gg[8] = {g0.x, g0.y, g0.z, g0.w, g1.x, g1.y, g1.z, g1.w};
  float bb[8] = {b0.x, b0.y, b0.z, b0.w, b1.x, b1.y, b1.z, b1.w};
  float o[8];
  #pragma unroll
  for (int j = 0; j < 8; j++) o[j] = (v[j] - mean) * inv * gg[j] + bb[j];
  if (Yb) {
    unsigned short u[8];
    #pragma unroll
    for (int j = 0; j < 8; j++) u[j] = f2bf(o[j]);
    *(uint4*)(Yb + (size_t)r * D_ + lane * 8) = *(const uint4*)u;
  }
  if (Yf) {
    float* dst = Yf + (size_t)r * D_ + lane * 8;
    *(float4*)(dst)     = (float4){o[0], o[1], o[2], o[3]};
    *(float4*)(dst + 4) = (float4){o[4], o[5], o[6], o[7]};
  }
}

// ---------------------------------------------------------------------------
// MFMA dual-stream cross-blended flash attention v2+T1+T5.
// Q-tile 128/block (4 waves x 32 q, 2 msets of 16). K-tiles of 64.
// QK computed TRANSPOSED (A=K,B=Q -> C'[key][q]) so P packs along regs ->
// Pl written as b64; K/V staged via global_load_lds into unpadded [64][64]
// tiles with XOR-chunk swizzle (conflict-free frag reads).
// Pl row stride 72 u16 (144 B = 9 bank-quads): reads 2 lanes/quad, writes
// 2 lanes/pair — both at the floor.
// T5: s_setprio(1) around MFMA clusters — the 4 waves run independent
// MFMA/VALU streams between the two per-tile barriers (m191-positive regime,
// not m190's lockstep-null), so the scheduler can favor MFMA-entering waves.
// T1 chunked swizzle: 8 q-blocks of one head colocate on an XCD.
// Plain exp (logits tiny) == exact softmax. 4 accumulators, blend at end.
// ---------------------------------------------------------------------------
__global__ __launch_bounds__(256, 2) void attn_kernel(
    const unsigned short* __restrict__ Qi, const unsigned short* __restrict__ Ki, int ldi,
    const unsigned short* __restrict__ Vti,
    const unsigned short* __restrict__ Qd, const unsigned short* __restrict__ Kd, int ldd,
    const unsigned short* __restrict__ Vtd,
    unsigned short* __restrict__ oi, unsigned short* __restrict__ od)
{
  __shared__ __align__(16) unsigned short Kls[2][64 * 64];   // [stream][key][dim] swizzled
  __shared__ __align__(16) unsigned short Vls[2][64 * 64];   // [stream][dim][key] swizzled
  __shared__ __align__(16) unsigned short Pl[4][2][16 * 72]; // [wave][stream][q][key] pad 72

  int tid = threadIdx.x;
  int phys = blockIdx.x + 8 * blockIdx.y;
  int L = xcd_swz(phys, 8 * 64);
  int bh = L >> 3, b = bh >> 3, h = bh & 7;
  int q0 = (L & 7) * 128;
  int lane = tid & 63, w = tid >> 6;
  int ml = lane & 15, g = lane >> 4;
  int mx = ml & 7;                       // row-swizzle term for frag reads

  // Q fragments: [mset][stream][khalf]; lane holds Q[q=ml of mset][dims g*8(+32)]
  short8 qf[2][2][2];
  #pragma unroll
  for (int t = 0; t < 2; t++) {
    size_t tok = (size_t)(q0 + w * 32 + t * 16 + ml) * B_ + b;
    const unsigned short* qa_i = Qi + tok * ldi + h * HD_ + g * 8;
    const unsigned short* qa_d = Qd + tok * ldd + h * HD_ + g * 8;
    qf[t][0][0] = *(const short8*)(qa_i);  qf[t][0][1] = *(const short8*)(qa_i + 32);
    qf[t][1][0] = *(const short8*)(qa_d);  qf[t][1][1] = *(const short8*)(qa_d + 32);
  }

  // staging role per wave: w0->K img, w1->K dpt, w2->V img, w3->V dpt
  int srow = lane >> 3;                  // 0..7
  int chg = (lane & 7) ^ srow;           // global chunk for this lane's LDS slot
  const unsigned short* gbase; size_t s1, s2; unsigned short* lbase;
  if (w == 0)      { gbase = Ki  + ((size_t)srow * B_ + b) * ldi + h * HD_ + chg * 8; s1 = (size_t)B_ * ldi; s2 = s1; lbase = &Kls[0][0]; }
  else if (w == 1) { gbase = Kd  + ((size_t)srow * B_ + b) * ldd + h * HD_ + chg * 8; s1 = (size_t)B_ * ldd; s2 = s1; lbase = &Kls[1][0]; }
  else if (w == 2) { gbase = Vti + (size_t)bh * HD_ * S_ + (size_t)srow * S_ + chg * 8; s1 = S_; s2 = 1; lbase = &Vls[0][0]; }
  else             { gbase = Vtd + (size_t)bh * HD_ * S_ + (size_t)srow * S_ + chg * 8; s1 = S_; s2 = 1; lbase = &Vls[1][0]; }

  f32x4 acc4[2][4][4];                   // [mset][combo: ii,di,id,dd][hd-tile]
  #pragma unroll
  for (int t = 0; t < 2; t++)
    #pragma unroll
    for (int cb = 0; cb < 4; cb++)
      #pragma unroll
      for (int n = 0; n < 4; n++) acc4[t][cb][n] = (f32x4){0.f, 0.f, 0.f, 0.f};
  float lI[2] = {0.f, 0.f}, lD[2] = {0.f, 0.f};
  const float scale = 0.125f;

  for (int kt = 0; kt < S_ / 64; kt++) {
    int k0 = kt * 64;
    __syncthreads();
    {
      const unsigned short* gp = gbase + (size_t)k0 * s2;
      #pragma unroll
      for (int rr = 0; rr < 8; rr++)
        gl_lds16(gp + (size_t)rr * 8 * s1, lbase + rr * 512);
    }
    __syncthreads();

    #pragma unroll
    for (int t = 0; t < 2; t++) {
      // ---- QK^T transposed: C'[key][q], key tiles n of 16 ----
      #pragma unroll
      for (int st = 0; st < 2; st++) {
        float* ls = st ? &lD[t] : &lI[t];
        const unsigned short* Kt = &Kls[st][0];
        #pragma unroll
        for (int n = 0; n < 4; n++) {
          int rbase = (n * 16 + ml) * 64;
          short8 kf0 = *(const short8*)&Kt[rbase + ((g ^ mx) * 8)];
          short8 kf1 = *(const short8*)&Kt[rbase + (((g + 4) ^ mx) * 8)];
          f32x4 a = (f32x4){0.f, 0.f, 0.f, 0.f};
          __builtin_amdgcn_s_setprio(1);
          a = __builtin_amdgcn_mfma_f32_16x16x32_bf16(kf0, qf[t][st][0], a, 0, 0, 0);
          a = __builtin_amdgcn_mfma_f32_16x16x32_bf16(kf1, qf[t][st][1], a, 0, 0, 0);
          __builtin_amdgcn_s_setprio(0);
          float p0 = __expf(a[0] * scale), p1 = __expf(a[1] * scale);
          float p2 = __expf(a[2] * scale), p3 = __expf(a[3] * scale);
          *ls += (p0 + p1) + (p2 + p3);
          uint2 pk; pk.x = pack_bf2(p0, p1); pk.y = pack_bf2(p2, p3);
          *(uint2*)&Pl[w][st][ml * 72 + n * 16 + g * 4] = pk;   // P[q=ml][key n*16+g*4..+3]
        }
      }
      // ---- PV: 4 combos, key-dim 64 in 2 chunks of 32 ----
      #pragma unroll
      for (int c = 0; c < 2; c++) {
        short8 pI = *(const short8*)&Pl[w][0][ml * 72 + g * 8 + c * 32];
        short8 pD = *(const short8*)&Pl[w][1][ml * 72 + g * 8 + c * 32];
        #pragma unroll
        for (int n = 0; n < 4; n++) {
          int rbase = (n * 16 + ml) * 64;
          int sc = (((g + 4 * c) ^ mx)) * 8;
          short8 vI = *(const short8*)&Vls[0][rbase + sc];
          short8 vD = *(const short8*)&Vls[1][rbase + sc];
          __builtin_amdgcn_s_setprio(1);
          acc4[t][0][n] = __builtin_amdgcn_mfma_f32_16x16x32_bf16(pI, vI, acc4[t][0][n], 0, 0, 0);
          acc4[t][1][n] = __builtin_amdgcn_mfma_f32_16x16x32_bf16(pD, vI, acc4[t][1][n], 0, 0, 0);
          acc4[t][2][n] = __builtin_amdgcn_mfma_f32_16x16x32_bf16(pI, vD, acc4[t][2][n], 0, 0, 0);
          acc4[t][3][n] = __builtin_amdgcn_mfma_f32_16x16x32_bf16(pD, vD, acc4[t][3][n], 0, 0, 0);
          __builtin_amdgcn_s_setprio(0);
        }
      }
    }
  }

  // denominators: lane holds partial (its 16 keys/ktile) for q=ml; reduce over g
  #pragma unroll
  for (int t = 0; t < 2; t++) {
    lI[t] += __shfl_xor(lI[t], 16);  lI[t] += __shfl_xor(lI[t], 32);
    lD[t] += __shfl_xor(lD[t], 16);  lD[t] += __shfl_xor(lD[t], 32);
  }
  #pragma unroll
  for (int t = 0; t < 2; t++) {
    float invI = 1.0f / lI[t], invD = 1.0f / lD[t];
    #pragma unroll
    for (int r = 0; r < 4; r++) {
      float iI = __shfl(invI, g * 4 + r, 16);     // denom lives at lane ml == q row
      float iD = __shfl(invD, g * 4 + r, 16);
      int qrow = q0 + w * 32 + t * 16 + g * 4 + r;
      size_t ob = ((size_t)qrow * B_ + b) * D_ + h * HD_;
      #pragma unroll
      for (int n = 0; n < 4; n++) {
        oi[ob + n * 16 + ml] = f2bf(0.5f * (acc4[t][0][n][r] * iI + acc4[t][1][n][r] * iD));
        od[ob + n * 16 + ml] = f2bf(0.5f * (acc4[t][3][n][r] * iD + acc4[t][2][n][r] * iI));
      }
    }
  }
}

// ---------------------------------------------------------------------------
extern "C" void kernel_launch(void* const* d_in, const int* in_sizes, int n_in,
                              void* d_out, int out_size, void* d_ws, size_t ws_size,
                              hipStream_t stream) {
  const float* src  = (const float*)d_in[0];
  const float* srcd = (const float*)d_in[1];
  const float* pos  = (const float*)d_in[2];
  const float* wA_i = (const float*)d_in[3];
  const float* bA_i = (const float*)d_in[4];
  const float* wA_d = (const float*)d_in[5];
  const float* bA_d = (const float*)d_in[6];
  const float* w1_i = (const float*)d_in[7];
  const float* b1_i = (const float*)d_in[8];
  const float* w2_i = (const float*)d_in[9];
  const float* b2_i = (const float*)d_in[10];
  const float* w1_d = (const float*)d_in[11];
  const float* b1_d = (const float*)d_in[12];
  const float* w2_d = (const float*)d_in[13];
  const float* b2_d = (const float*)d_in[14];
  const float* ln_i = (const float*)d_in[15];
  const float* ln_d = (const float*)d_in[16];

  float* out = (float*)d_out;
  unsigned short* u = (unsigned short*)d_ws;
  const size_t T4 = (size_t)M_ * D_;          // 4,194,304
  const size_t WSZ = (size_t)FF_ * D_;        // 1,048,576 (== 4*DD_)

  // ---- workspace layout (units of T4 ushorts = 8.39 MB; total 113.2 MB) ----
  unsigned short* src16  = u;                 // [0,1) -> vt_i after QKV
  unsigned short* srcd16 = u + T4;            // [1,2) -> vt_d after QKV
  unsigned short* qkimg  = u + 2 * T4;        // [2,4)  [M,1024]
  unsigned short* vimg   = u + 4 * T4;        // [4,5)  [M,512]
  unsigned short* dptqkv = u + 5 * T4;        // [5,8)  [M,1536]
  unsigned short* w_i16  = u + 8 * T4;        // weights: 6 x 1,048,576
  unsigned short* w_d16  = w_i16 + WSZ;
  unsigned short* w1i16  = w_d16 + WSZ;
  unsigned short* w2i16  = w1i16 + WSZ;
  unsigned short* w1d16  = w2i16 + WSZ;
  unsigned short* w2d16  = w1d16 + WSZ;
  unsigned short* t16_i  = w2d16 + WSZ;       // [9.5,10.5) pre-LN bf16
  unsigned short* t16_d  = t16_i + T4;        // [10.5,11.5)
  unsigned short* x16_i  = t16_d + T4;        // [11.5,12.5) post-LN1
  unsigned short* x16_d  = x16_i + T4;        // [12.5,13.5)
  unsigned short* vt_i   = src16;             // reuse after QKV
  unsigned short* vt_d   = srcd16;
  unsigned short* h16_i  = u;                 // [0,4) FFN hidden (post-attn reuse)
  unsigned short* h16_d  = u + 4 * T4;        // [4,8)
  // d_out overlays (consumed before final LN writes)
  unsigned short* qkin16 = (unsigned short*)out;          // bytes [0, 2T4)
  unsigned short* oi16   = (unsigned short*)out;          // bytes [0, 2T4)
  unsigned short* od16   = (unsigned short*)out + T4;     // bytes [2T4, 4T4)

  dim3 blk(256);

  CvtArgs ca;
  ca.win[0] = wA_i; ca.wout[0] = w_i16;
  ca.win[1] = wA_d; ca.wout[1] = w_d16;
  ca.win[2] = w1_i; ca.wout[2] = w1i16;
  ca.win[3] = w2_i; ca.wout[3] = w2i16;
  ca.win[4] = w1_d; ca.wout[4] = w1d16;
  ca.win[5] = w2_d; ca.wout[5] = w2d16;
  ca.src = src; ca.srcd = srcd; ca.pos = pos;
  ca.src16 = src16; ca.srcd16 = srcd16; ca.qkin16 = qkin16;
  cvt_kernel<<<dim3(18432), blk, 0, stream>>>(ca);

  qkv_kernel<<<dim3(24, 64), blk, 0, stream>>>(qkin16, src16, srcd16, w_i16, w_d16,
                                               bA_i, bA_d, qkimg, vimg, dptqkv);
  vtrans_kernel<<<dim3(16, 64, 2), blk, 0, stream>>>(vimg, 512, vt_i, dptqkv + 1024, 1536, vt_d);

  attn_kernel<<<dim3(S_ / 128, B_ * H_), blk, 0, stream>>>(
      qkimg, qkimg + 512, 1024, vt_i, dptqkv, dptqkv + 512, 1536, vt_d, oi16, od16);

  // out-proj + residual(src fp32) -> pre-LN bf16
  pgemm_kernel<<<dim3(4, 64, 2), blk, 0, stream>>>(
      oi16, od16, w_i16 + 3 * DD_, w_d16 + 3 * DD_, bA_i + 1536, bA_d + 1536,
      src, srcd, nullptr, nullptr, t16_i, t16_d, 512, 512, 0);
  ln16_kernel<<<dim3(2 * M_ / 4), blk, 0, stream>>>(t16_i, t16_d, x16_i, x16_d,
                                                    nullptr, nullptr, ln_i, ln_d);
  pgemm_kernel<<<dim3(16, 64, 2), blk, 0, stream>>>(
      x16_i, x16_d, w1i16, w1d16, b1_i, b1_d,
      nullptr, nullptr, nullptr, nullptr, h16_i, h16_d, 2048, 512, 1);
  pgemm_kernel<<<dim3(4, 64, 2), blk, 0, stream>>>(
      h16_i, h16_d, w2i16, w2d16, b2_i, b2_d,
      nullptr, nullptr, x16_i, x16_d, t16_i, t16_d, 512, 2048, 0);
  ln16_kernel<<<dim3(2 * M_ / 4), blk, 0, stream>>>(t16_i, t16_d, nullptr, nullptr,
                                                    out, out + T4, ln_i + 2 * D_, ln_d + 2 * D_);
}